// Round 3
// baseline (4299.503 us; speedup 1.0000x reference)
//
#include <hip/hip_runtime.h>

#define TT 512
#define FF 16
#define HH 256
#define OUTLEN 64
#define NT 9          // K tiles of 32 -> K=288 (h 0..255, bias 256, x/inp 257..272, pad)
#define PITCH 296     // uH/uL row pitch in halfs; 2-way-max bank aliasing on A reads
#define ROWS 16       // batch rows per block -> 256 blocks, 1 per CU
#define NBLK (4096/ROWS)
#define NFRAG (NT*16*4*64)   // half8 fragments per phase = 36864 (589824 B)
//
// R3 design: ONE barrier per encoder step via double-buffered activations.
//   R1/R2 post-mortem: register-pinning kt2..4 never materialized (VGPR stuck
//   at 64 both rounds; FETCH rose). Root cause of the 42% no-issue cycles is
//   NOT the allocator: the 2-barrier step serializes {stream | MFMA | VALU}
//   across all 16 waves. Fix is structural:
//     read A from buf[p], write h(t) + x(t+1) into buf[p^1], ONE barrier.
//   A wave leaving its MFMAs immediately runs its (acc is wave-local) cell
//   update while other waves still issue MFMAs -> VALU overlaps MAI, and one
//   barrier drain per step is gone.
// LDS: 2x(uH+uL) = 37 KB + Bt 112 KB (kt0 + kt1 g0..2) + red 1 KB = 150 KB.
//   kt1 g3 (4 VGPRs) is register-pinned; if the compiler sinks it, it merely
//   joins the stream (harmless).
// Stream: kt2..8 (448 KB/CU/step) with R0's proven cross-step rotation
//   (refills at s=5,6 fetch NEXT step's kt3,kt2).

typedef _Float16 half8 __attribute__((ext_vector_type(8)));
typedef float f32x4 __attribute__((ext_vector_type(4)));

// 1-ulp rcp instead of the ~10-instr exact-division sequence (no fast-math here)
__device__ __forceinline__ float fsig(float x) {
  return __builtin_amdgcn_rcpf(1.0f + __expf(-x));
}
__device__ __forceinline__ float ftanh(float x) { return 2.0f * fsig(x + x) - 1.0f; }

// frag half8 idx = ((kt*16 + w)*4 + g)*64 + lane
//   col = g*256 + w*16 + (lane&15);  k = kt*32 + (lane>>4)*8 + j
__global__ void prep_kernel(const float* __restrict__ eWih, const float* __restrict__ eWhh,
                            const float* __restrict__ eb,  const float* __restrict__ dWih,
                            const float* __restrict__ dWhh, const float* __restrict__ db,
                            _Float16* __restrict__ E, _Float16* __restrict__ D) {
  int idx = blockIdx.x * 256 + threadIdx.x;
  if (idx >= NFRAG * 8) return;
  int j    = idx & 7;
  int lane = (idx >> 3) & 63;
  int rest = idx >> 9;         // (kt*16 + w)*4 + g
  int g    = rest & 3;
  int wv   = (rest >> 2) & 15;
  int kt   = rest >> 6;
  int col  = g * 256 + wv * 16 + (lane & 15);
  int k    = kt * 32 + (lane >> 4) * 8 + j;
  float ve = 0.f, vd = 0.f;
  if (k < HH)        { ve = eWhh[col * HH + k]; vd = dWhh[col * HH + k]; }
  else if (k == HH)  { ve = eb[col];            vd = db[col]; }
  else if (k <= 272) { ve = eWih[col * FF + (k - 257)]; if (k == 257) vd = dWih[col]; }
  E[idx] = (_Float16)ve;
  D[idx] = (_Float16)vd;
}

// strm points at kt2 base. Prologue: kt2 -> bf[0], kt3 -> bf[1].
__device__ __forceinline__ void fill_bf(half8 (&bf)[2][4], const half8* __restrict__ strm) {
#pragma unroll
  for (int g = 0; g < 4; ++g) bf[0][g] = strm[0 * 4096 + g * 64];  // kt2
#pragma unroll
  for (int g = 0; g < 4; ++g) bf[1][g] = strm[1 * 4096 + g * 64];  // kt3
}

// One step's matvec for this wave's 64 gate columns.
//   kt0      from LDS (Btp0), kt1 g0..2 from LDS (Btp1), kt1 g3 pinned (pkx)
//   kt2..8   streamed: consume bf[s&1], refill s<5 -> this step's kt(4+s),
//            s=5 -> next step's kt3, s=6 -> next step's kt2.
__device__ __forceinline__ void mfma_step(const _Float16* __restrict__ uHp,
                                          const _Float16* __restrict__ uLp,
                                          const half8* __restrict__ Btp0,
                                          const half8* __restrict__ Btp1,
                                          const half8* __restrict__ strm,
                                          const half8 pkx,
                                          half8 (&bf)[2][4],
                                          f32x4 (&acc)[4]) {
#pragma unroll
  for (int g = 0; g < 4; ++g) acc[g] = (f32x4){0.f, 0.f, 0.f, 0.f};

  {  // kt0 (LDS)
    half8 b[4];
#pragma unroll
    for (int g = 0; g < 4; ++g) b[g] = Btp0[g * 64];
    half8 AH = *(const half8*)(uHp);
    half8 AL = *(const half8*)(uLp);
#pragma unroll
    for (int g = 0; g < 4; ++g) acc[g] = __builtin_amdgcn_mfma_f32_16x16x32_f16(AH, b[g], acc[g], 0, 0, 0);
#pragma unroll
    for (int g = 0; g < 4; ++g) acc[g] = __builtin_amdgcn_mfma_f32_16x16x32_f16(AL, b[g], acc[g], 0, 0, 0);
  }
  {  // kt1 (LDS g0..2 + pinned g3)
    half8 b[4];
#pragma unroll
    for (int g = 0; g < 3; ++g) b[g] = Btp1[g * 64];
    b[3] = pkx;
    half8 AH = *(const half8*)(uHp + 32);
    half8 AL = *(const half8*)(uLp + 32);
#pragma unroll
    for (int g = 0; g < 4; ++g) acc[g] = __builtin_amdgcn_mfma_f32_16x16x32_f16(AH, b[g], acc[g], 0, 0, 0);
#pragma unroll
    for (int g = 0; g < 4; ++g) acc[g] = __builtin_amdgcn_mfma_f32_16x16x32_f16(AL, b[g], acc[g], 0, 0, 0);
  }

#pragma unroll
  for (int s = 0; s < 7; ++s) {      // kt = 2+s, consume bf[s&1]
    half8 AH = *(const half8*)(uHp + (2 + s) * 32);
    half8 AL = *(const half8*)(uLp + (2 + s) * 32);
#pragma unroll
    for (int g = 0; g < 4; ++g) acc[g] = __builtin_amdgcn_mfma_f32_16x16x32_f16(AH, bf[s & 1][g], acc[g], 0, 0, 0);
#pragma unroll
    for (int g = 0; g < 4; ++g) acc[g] = __builtin_amdgcn_mfma_f32_16x16x32_f16(AL, bf[s & 1][g], acc[g], 0, 0, 0);
    {  // refill: s<5 -> this step's kt 4+s; s=5 -> next kt3; s=6 -> next kt2
      const int off = (s < 5) ? (s + 2) : (6 - s);
      const half8* rp = strm + off * 4096;
#pragma unroll
      for (int g = 0; g < 4; ++g) bf[s & 1][g] = rp[g * 64];
    }
  }
}

// 256 blocks x 1024 threads (16 waves, 4/SIMD). Block owns 16 batch rows and all
// 1024 gate columns -> zero inter-block communication. Wave w: unit = w*16+(lane&15),
// rows m = quad*4+rg -> cc[4] lane-local across all 576 steps.
__global__ __launch_bounds__(1024, 4) void seq2seq_kernel(
    const float* __restrict__ x,
    const _Float16* __restrict__ E, const _Float16* __restrict__ Dw,
    const float* __restrict__ Wout, const float* __restrict__ bout,
    float* __restrict__ out) {
  __shared__ _Float16 uHa[ROWS * PITCH];  // 9.25 KB activation hi, buffer A
  __shared__ _Float16 uLa[ROWS * PITCH];  // 9.25 KB activation lo, buffer A
  __shared__ _Float16 uHb[ROWS * PITCH];  // buffer B
  __shared__ _Float16 uLb[ROWS * PITCH];
  __shared__ half8 Bt[7168];              // 112 KB: kt0 full + kt1 g0..2
  __shared__ float red[ROWS * 16];        // 1 KB head partials [row][wave]
  // 150 KB total -> 1 block/CU

  const int tid  = threadIdx.x;
  const int w    = tid >> 6;
  const int lane = tid & 63;
  const int quad = lane >> 4;
  const int l15  = lane & 15;
  const int b0   = blockIdx.x * ROWS;
  const int unit = w * 16 + l15;

  const half8* E8 = (const half8*)E;
  const half8* D8 = (const half8*)Dw;

  for (int i = tid; i < ROWS * PITCH; i += 1024) {
    uHa[i] = (_Float16)0.f; uLa[i] = (_Float16)0.f;
    uHb[i] = (_Float16)0.f; uLb[i] = (_Float16)0.f;
  }
  // Bt load with kt1 g3 squeezed out: slot i<4096 -> kt0; else kt1 g0..2.
  for (int i = tid; i < 7168; i += 1024)
    Bt[i] = E8[i < 4096 ? i : i + ((i - 4096) / 192) * 64];
  __syncthreads();

  const int   xr  = (tid >> 4) * PITCH + 257 + (tid & 15);
  const float* xp = x + ((long)(b0 + (tid >> 4)) * TT) * FF + (tid & 15);

  float xv = 0.f;
  if (tid < ROWS) { uHa[tid * PITCH + 256] = (_Float16)1.0f;   // bias-one col, both bufs
                    uHb[tid * PITCH + 256] = (_Float16)1.0f; }
  if (tid < 256) {                      // stage x(0) into buffer A; prefetch x(1)
    xv = xp[0];
    _Float16 hs = (_Float16)xv;
    uHa[xr] = hs; uLa[xr] = (_Float16)(xv - (float)hs);
    xv = xp[FF];
  }

  const int aoff = l15 * PITCH + quad * 8;
  const half8* Btp0 = Bt + w * 256 + lane;          // kt0 frags [g*64]
  const half8* Btp1 = Bt + 4096 + w * 192 + lane;   // kt1 g0..2 frags [g*64]
  const half8* strm = E8 + 2 * 4096 + w * 256 + lane;  // kt2 base

  float cc[4] = {0.f, 0.f, 0.f, 0.f};
  const float wou = Wout[unit];
  const float bo  = bout[0];

  half8 pkx = E8[4096 + w * 256 + 3 * 64 + lane];   // kt1 g3 pinned (4 VGPRs)
  asm volatile("" : "+v"(pkx));
  half8 bf[2][4];
  fill_bf(bf, strm);                     // prologue: kt2,kt3 in flight
  __syncthreads();                       // bias + x(0) visible

  _Float16 *cH = uHa, *cL = uLa, *nH = uHb, *nL = uLb;

  // ---------------- encoder: 512 steps, ONE barrier each ----------------
#pragma unroll 1
  for (int t = 0; t < TT; ++t) {
    if (tid < 256 && t < TT - 1) {       // stage x(t+1) into NXT (nobody reads nxt this step)
      _Float16 hs = (_Float16)xv;
      nH[xr] = hs; nL[xr] = (_Float16)(xv - (float)hs);
      if (t < TT - 2) xv = xp[(t + 2) * FF];
    }

    f32x4 acc[4];
    mfma_step(cH + aoff, cL + aoff, Btp0, Btp1, strm, pkx, bf, acc);

#pragma unroll
    for (int rg = 0; rg < 4; ++rg) {     // cell update -> write h(t) into NXT
      float ig = fsig(acc[0][rg]);
      float fg = fsig(acc[1][rg]);
      float gg = ftanh(acc[2][rg]);
      float og = fsig(acc[3][rg]);
      cc[rg] = fg * cc[rg] + ig * gg;
      float hv = og * ftanh(cc[rg]);
      const int m = quad * 4 + rg;
      _Float16 hs = (_Float16)hv;
      nH[m * PITCH + unit] = hs;
      nL[m * PITCH + unit] = (_Float16)(hv - (float)hs);
    }
    __syncthreads();                     // nxt complete; everyone may flip
    _Float16* tp;
    tp = cH; cH = nH; nH = tp;
    tp = cL; cL = nL; nL = tp;
  }

  // ---- phase swap: decoder tier + pinned frag + stream base ----
  // (last encoder barrier already ordered all Bt reads before this rewrite)
  for (int i = tid; i < 7168; i += 1024)
    Bt[i] = D8[i < 4096 ? i : i + ((i - 4096) / 192) * 64];
  strm = D8 + 2 * 4096 + w * 256 + lane;
  pkx = D8[4096 + w * 256 + 3 * 64 + lane];
  asm volatile("" : "+v"(pkx));
  fill_bf(bf, strm);                     // overwrite stale encoder kt2,kt3
  if (tid < ROWS) { cH[tid * PITCH + 257] = (_Float16)0.f;  // inp0 = 0 in CUR
                    cL[tid * PITCH + 257] = (_Float16)0.f; }
  // stale x cols 258..272 (both buffers): decoder weight rows there are zero.
  __syncthreads();

  // ---------------- decoder: 64 autoregressive steps (2 barriers: red dep) ----------------
#pragma unroll 1
  for (int td = 0; td < OUTLEN; ++td) {
    f32x4 acc[4];
    mfma_step(cH + aoff, cL + aoff, Btp0, Btp1, strm, pkx, bf, acc);

    float p[4];
#pragma unroll
    for (int rg = 0; rg < 4; ++rg) {     // cell update -> write h into NXT
      float ig = fsig(acc[0][rg]);
      float fg = fsig(acc[1][rg]);
      float gg = ftanh(acc[2][rg]);
      float og = fsig(acc[3][rg]);
      cc[rg] = fg * cc[rg] + ig * gg;
      float hv = og * ftanh(cc[rg]);
      const int m = quad * 4 + rg;
      _Float16 hs = (_Float16)hv;
      nH[m * PITCH + unit] = hs;
      nL[m * PITCH + unit] = (_Float16)(hv - (float)hs);
      p[rg] = hv * wou;
    }
    // head: sum this wave's 16 units (lanes of a quad share rows)
#pragma unroll
    for (int off = 1; off < 16; off <<= 1)
#pragma unroll
      for (int rg = 0; rg < 4; ++rg) p[rg] += __shfl_xor(p[rg], off, 64);
    if (l15 == 0) {
#pragma unroll
      for (int rg = 0; rg < 4; ++rg) red[(quad * 4 + rg) * 16 + w] = p[rg];
    }
    __syncthreads();                     // red + h-writes complete
    if (tid < ROWS) {                    // sum 16 waves -> out + feedback into NXT
      float s = bo;
#pragma unroll
      for (int u = 0; u < 16; ++u) s += red[tid * 16 + u];
      out[(long)(b0 + tid) * OUTLEN + td] = s;
      _Float16 hs = (_Float16)s;
      nH[tid * PITCH + 257] = hs;
      nL[tid * PITCH + 257] = (_Float16)(s - (float)hs);
    }
    __syncthreads();                     // inp visible before flip
    _Float16* tp;
    tp = cH; cH = nH; nH = tp;
    tp = cL; cL = nL; nL = tp;
  }
}

extern "C" void kernel_launch(void* const* d_in, const int* in_sizes, int n_in,
                              void* d_out, int out_size, void* d_ws, size_t ws_size,
                              hipStream_t stream) {
  const float* x    = (const float*)d_in[0];
  const float* eWih = (const float*)d_in[1];
  const float* eWhh = (const float*)d_in[2];
  const float* eb   = (const float*)d_in[3];
  const float* dWih = (const float*)d_in[4];
  const float* dWhh = (const float*)d_in[5];
  const float* db   = (const float*)d_in[6];
  const float* Wout = (const float*)d_in[7];
  const float* bout = (const float*)d_in[8];
  float* out = (float*)d_out;

  _Float16* E  = (_Float16*)d_ws;        // 589824 B
  _Float16* Dw = E + NFRAG * 8;          // 589824 B

  prep_kernel<<<dim3((NFRAG * 8 + 255) / 256), dim3(256), 0, stream>>>(
      eWih, eWhh, eb, dWih, dWhh, db, E, Dw);
  seq2seq_kernel<<<dim3(NBLK), dim3(1024), 0, stream>>>(
      x, E, Dw, Wout, bout, out);
}

// Round 4
// 2899.374 us; speedup vs baseline: 1.4829x; 1.4829x over previous
//
#include <hip/hip_runtime.h>

#define TT 512
#define FF 16
#define HH 256
#define OUTLEN 64
#define NT 9          // K tiles of 32 -> K=288 (h 0..255, bias 256, x/inp 257..272, pad)
#define PITCH 296     // uH/uL row pitch in halfs; 2-way-max bank aliasing on A reads
#define ROWS 16       // batch rows per block -> 256 blocks, 1 per CU
#define NBLK (4096/ROWS)
#define NFRAG (NT*16*4*64)   // half8 fragments per phase = 36864 (589824 B)
// B residency (3 tiers), R4:
//   kt0,1  -> 128 KB LDS tier
//   kt2,3,4 -> REGISTER-PINNED per wave (48 VGPRs). R1/R2 post-mortem: a
//              fill-time-only asm pin is sunk by the allocator (VGPR stayed
//              64). R4 makes the pin LOOP-CARRIED: an empty
//              asm volatile("+v") on every fragment INSIDE the step loop
//              consumes-and-redefines the value each iteration -> cannot be
//              rematerialized as a load; must live in VGPRs (112 <= 128
//              budget at 4 waves/SIMD) or spill (would show in WRITE_SIZE).
//   kt5..8 -> streamed (256 KB/step, was 448) with cross-step double buffer.
//              Order: stream s=0,1 (refill 7,8) -> LDS kt0,1 -> stream s=2,3
//              (refill NEXT step's 5,6) -> pinned tail; next-step prefetch
//              drains under pinned MFMAs + cell update + both barriers.
// R3 post-mortem: single-barrier + drift RAISED L2-miss traffic on the
// shared weight lines (FETCH 8.9->13.4 GB) and cost +16% -- the 2-barrier
// step stays.

typedef _Float16 half8 __attribute__((ext_vector_type(8)));
typedef float f32x4 __attribute__((ext_vector_type(4)));

// 1-ulp rcp instead of the ~10-instr exact-division sequence (no fast-math here)
__device__ __forceinline__ float fsig(float x) {
  return __builtin_amdgcn_rcpf(1.0f + __expf(-x));
}
__device__ __forceinline__ float ftanh(float x) { return 2.0f * fsig(x + x) - 1.0f; }

// frag half8 idx = ((kt*16 + w)*4 + g)*64 + lane
//   col = g*256 + w*16 + (lane&15);  k = kt*32 + (lane>>4)*8 + j
__global__ void prep_kernel(const float* __restrict__ eWih, const float* __restrict__ eWhh,
                            const float* __restrict__ eb,  const float* __restrict__ dWih,
                            const float* __restrict__ dWhh, const float* __restrict__ db,
                            _Float16* __restrict__ E, _Float16* __restrict__ D) {
  int idx = blockIdx.x * 256 + threadIdx.x;
  if (idx >= NFRAG * 8) return;
  int j    = idx & 7;
  int lane = (idx >> 3) & 63;
  int rest = idx >> 9;         // (kt*16 + w)*4 + g
  int g    = rest & 3;
  int wv   = (rest >> 2) & 15;
  int kt   = rest >> 6;
  int col  = g * 256 + wv * 16 + (lane & 15);
  int k    = kt * 32 + (lane >> 4) * 8 + j;
  float ve = 0.f, vd = 0.f;
  if (k < HH)        { ve = eWhh[col * HH + k]; vd = dWhh[col * HH + k]; }
  else if (k == HH)  { ve = eb[col];            vd = db[col]; }
  else if (k <= 272) { ve = eWih[col * FF + (k - 257)]; if (k == 257) vd = dWih[col]; }
  E[idx] = (_Float16)ve;
  D[idx] = (_Float16)vd;
}

// strm points at kt5 base. Prologue: kt5 -> bf[0], kt6 -> bf[1].
__device__ __forceinline__ void fill_bf(half8 (&bf)[2][4], const half8* __restrict__ strm) {
#pragma unroll
  for (int g = 0; g < 4; ++g) bf[0][g] = strm[0 * 4096 + g * 64];  // kt5
#pragma unroll
  for (int g = 0; g < 4; ++g) bf[1][g] = strm[1 * 4096 + g * 64];  // kt6
}

// pp points at kt2 base. Load kt2,3,4 for this wave's 64 gate columns.
// Residency is enforced by the IN-LOOP pin (see step loops), not here.
__device__ __forceinline__ void fill_pk(half8 (&pk)[3][4], const half8* __restrict__ pp) {
#pragma unroll
  for (int i = 0; i < 3; ++i)
#pragma unroll
    for (int g = 0; g < 4; ++g) pk[i][g] = pp[i * 4096 + g * 64];
}

// Loop-carried register pin: consume-and-redefine every pinned fragment.
// Zero instructions; creates a cross-iteration VGPR dependence the
// allocator cannot break by re-loading.
#define PIN_PK(pk)                                                   \
  _Pragma("unroll")                                                  \
  for (int _i = 0; _i < 3; ++_i)                                     \
    _Pragma("unroll")                                                \
    for (int _g = 0; _g < 4; ++_g)                                   \
      asm volatile("" : "+v"(pk[_i][_g]));

// One step's matvec for this wave's 64 gate columns.
//   stream s=0,1 (kt5,kt6; refill kt7,kt8) -> LDS tier kt0,1 ->
//   stream s=2,3 (kt7,kt8; refill NEXT step's kt5,kt6) -> pinned kt2,3,4.
__device__ __forceinline__ void mfma_step(const _Float16* __restrict__ uHp,
                                          const _Float16* __restrict__ uLp,
                                          const half8* __restrict__ Btp,
                                          const half8* __restrict__ strm,
                                          const half8 (&pk)[3][4],
                                          half8 (&bf)[2][4],
                                          f32x4 (&acc)[4]) {
#pragma unroll
  for (int g = 0; g < 4; ++g) acc[g] = (f32x4){0.f, 0.f, 0.f, 0.f};

#pragma unroll
  for (int s = 0; s < 2; ++s) {      // kt = 5+s, consume bf[s]
    half8 AH = *(const half8*)(uHp + (5 + s) * 32);
    half8 AL = *(const half8*)(uLp + (5 + s) * 32);
#pragma unroll
    for (int g = 0; g < 4; ++g) acc[g] = __builtin_amdgcn_mfma_f32_16x16x32_f16(AH, bf[s][g], acc[g], 0, 0, 0);
#pragma unroll
    for (int g = 0; g < 4; ++g) acc[g] = __builtin_amdgcn_mfma_f32_16x16x32_f16(AL, bf[s][g], acc[g], 0, 0, 0);
    {  // refill kt7 (s=0) / kt8 (s=1); consumed after the LDS tier below
      const half8* rp = strm + (s + 2) * 4096;
#pragma unroll
      for (int g = 0; g < 4; ++g) bf[s][g] = rp[g * 64];
    }
  }

#pragma unroll
  for (int kt = 0; kt < 2; ++kt) {   // LDS tier -- gives s=0,1 refills ~160cy lead
    half8 b[4];
#pragma unroll
    for (int g = 0; g < 4; ++g) b[g] = Btp[kt * 4096 + g * 64];
    half8 AH = *(const half8*)(uHp + kt * 32);
    half8 AL = *(const half8*)(uLp + kt * 32);
#pragma unroll
    for (int g = 0; g < 4; ++g) acc[g] = __builtin_amdgcn_mfma_f32_16x16x32_f16(AH, b[g], acc[g], 0, 0, 0);
#pragma unroll
    for (int g = 0; g < 4; ++g) acc[g] = __builtin_amdgcn_mfma_f32_16x16x32_f16(AL, b[g], acc[g], 0, 0, 0);
  }

#pragma unroll
  for (int s = 2; s < 4; ++s) {      // kt = 5+s, consume bf[s-2]
    half8 AH = *(const half8*)(uHp + (5 + s) * 32);
    half8 AL = *(const half8*)(uLp + (5 + s) * 32);
#pragma unroll
    for (int g = 0; g < 4; ++g) acc[g] = __builtin_amdgcn_mfma_f32_16x16x32_f16(AH, bf[s - 2][g], acc[g], 0, 0, 0);
#pragma unroll
    for (int g = 0; g < 4; ++g) acc[g] = __builtin_amdgcn_mfma_f32_16x16x32_f16(AL, bf[s - 2][g], acc[g], 0, 0, 0);
    {  // refill NEXT step's kt5 (s=2) / kt6 (s=3); drains under pinned tail
      const half8* rp = strm + (s - 2) * 4096;
#pragma unroll
      for (int g = 0; g < 4; ++g) bf[s - 2][g] = rp[g * 64];
    }
  }

#pragma unroll
  for (int i = 0; i < 3; ++i) {      // pinned tier kt2,3,4 (zero memory traffic)
    half8 AH = *(const half8*)(uHp + (2 + i) * 32);
    half8 AL = *(const half8*)(uLp + (2 + i) * 32);
#pragma unroll
    for (int g = 0; g < 4; ++g) acc[g] = __builtin_amdgcn_mfma_f32_16x16x32_f16(AH, pk[i][g], acc[g], 0, 0, 0);
#pragma unroll
    for (int g = 0; g < 4; ++g) acc[g] = __builtin_amdgcn_mfma_f32_16x16x32_f16(AL, pk[i][g], acc[g], 0, 0, 0);
  }
}

// 256 blocks x 1024 threads (16 waves, 4/SIMD). Block owns 16 batch rows and all
// 1024 gate columns -> zero inter-block communication. Wave w: unit = w*16+(lane&15),
// rows m = quad*4+rg -> cc[4] lane-local across all 576 steps.
__global__ __launch_bounds__(1024, 4) void seq2seq_kernel(
    const float* __restrict__ x,
    const _Float16* __restrict__ E, const _Float16* __restrict__ Dw,
    const float* __restrict__ Wout, const float* __restrict__ bout,
    float* __restrict__ out) {
  __shared__ _Float16 uH[ROWS * PITCH];  // 9.25 KB activation hi [m][k]
  __shared__ _Float16 uL[ROWS * PITCH];  // 9.25 KB activation lo
  __shared__ half8 Bt[2 * 16 * 4 * 64];  // 128 KB  kt0,1 B tier (frag order)
  __shared__ float red[ROWS * 16];       // 1 KB   head partials [row][wave]
  // 147.5 KB total -> 1 block/CU

  const int tid  = threadIdx.x;
  const int w    = tid >> 6;
  const int lane = tid & 63;
  const int quad = lane >> 4;
  const int l15  = lane & 15;
  const int b0   = blockIdx.x * ROWS;
  const int unit = w * 16 + l15;

  const half8* E8 = (const half8*)E;
  const half8* D8 = (const half8*)Dw;

  for (int i = tid; i < ROWS * PITCH; i += 1024) { uH[i] = (_Float16)0.f; uL[i] = (_Float16)0.f; }
  for (int i = tid; i < 8192; i += 1024) Bt[i] = E8[i];   // kt0,1 tier (encoder)
  __syncthreads();
  if (tid < ROWS) uH[tid * PITCH + 256] = (_Float16)1.0f; // bias-one column

  const _Float16* uHp = uH + l15 * PITCH + quad * 8;
  const _Float16* uLp = uL + l15 * PITCH + quad * 8;
  const half8* Btp  = Bt + w * 256 + lane;                // [kt*4096 + g*64]
  const half8* strm = E8 + 5 * 4096 + w * 256 + lane;     // kt5 base, streamed tier

  float cc[4] = {0.f, 0.f, 0.f, 0.f};
  const float wou = Wout[unit];
  const float bo  = bout[0];
  const int   xr  = (tid >> 4) * PITCH + 257 + (tid & 15);
  const float* xp = x + ((long)(b0 + (tid >> 4)) * TT) * FF + (tid & 15);

  half8 pk[3][4];
  fill_pk(pk, E8 + 2 * 4096 + w * 256 + lane);  // load kt2,3,4 (encoder)
  half8 bf[2][4];
  fill_bf(bf, strm);                     // prologue: kt5,kt6 in flight

  // ---------------- encoder: 512 steps ----------------
  float xv = (tid < 256) ? xp[0] : 0.f;
#pragma unroll 1
  for (int t = 0; t < TT; ++t) {
    PIN_PK(pk);                          // loop-carried pin: kt2,3,4 stay in VGPRs
    if (tid < 256) {                     // stage x(t): 16 rows x 16 features, hi/lo
      _Float16 hs = (_Float16)xv;
      uH[xr] = hs; uL[xr] = (_Float16)(xv - (float)hs);
      if (t + 1 < TT) xv = xp[(t + 1) * FF];
    }
    __syncthreads();                     // h(t-1) + x(t) visible

    f32x4 acc[4];
    mfma_step(uHp, uLp, Btp, strm, pk, bf, acc);
    __syncthreads();                     // all A reads done before h overwrite

#pragma unroll
    for (int rg = 0; rg < 4; ++rg) {
      float ig = fsig(acc[0][rg]);
      float fg = fsig(acc[1][rg]);
      float gg = ftanh(acc[2][rg]);
      float og = fsig(acc[3][rg]);
      cc[rg] = fg * cc[rg] + ig * gg;
      float hv = og * ftanh(cc[rg]);
      const int m = quad * 4 + rg;
      _Float16 hs = (_Float16)hv;
      uH[m * PITCH + unit] = hs;
      uL[m * PITCH + unit] = (_Float16)(hv - (float)hs);
    }
  }

  // ---- phase swap: decoder tier + pinned regs + stream base ----
  __syncthreads();
  for (int i = tid; i < 8192; i += 1024) Bt[i] = D8[i];
  strm = D8 + 5 * 4096 + w * 256 + lane;
  fill_pk(pk, D8 + 2 * 4096 + w * 256 + lane);  // re-load kt2,3,4 (decoder)
  fill_bf(bf, strm);                     // overwrite stale encoder kt5,kt6
  if (tid < ROWS) { uH[tid * PITCH + 257] = (_Float16)0.f; uL[tid * PITCH + 257] = (_Float16)0.f; }
  // stale x cols 258..272: decoder weight rows there are zero -> no contribution

  // ---------------- decoder: 64 autoregressive steps ----------------
#pragma unroll 1
  for (int td = 0; td < OUTLEN; ++td) {
    PIN_PK(pk);                          // loop-carried pin (decoder weights)
    __syncthreads();                     // tier + h + inp visible

    f32x4 acc[4];
    mfma_step(uHp, uLp, Btp, strm, pk, bf, acc);
    __syncthreads();                     // reads done before overwrite

    float p[4];
#pragma unroll
    for (int rg = 0; rg < 4; ++rg) {
      float ig = fsig(acc[0][rg]);
      float fg = fsig(acc[1][rg]);
      float gg = ftanh(acc[2][rg]);
      float og = fsig(acc[3][rg]);
      cc[rg] = fg * cc[rg] + ig * gg;
      float hv = og * ftanh(cc[rg]);
      const int m = quad * 4 + rg;
      _Float16 hs = (_Float16)hv;
      uH[m * PITCH + unit] = hs;
      uL[m * PITCH + unit] = (_Float16)(hv - (float)hs);
      p[rg] = hv * wou;
    }
    // head: sum this wave's 16 units (lanes of a quad share rows)
#pragma unroll
    for (int off = 1; off < 16; off <<= 1)
#pragma unroll
      for (int rg = 0; rg < 4; ++rg) p[rg] += __shfl_xor(p[rg], off, 64);
    if (l15 == 0) {
#pragma unroll
      for (int rg = 0; rg < 4; ++rg) red[(quad * 4 + rg) * 16 + w] = p[rg];
    }
    __syncthreads();
    if (tid < ROWS) {                    // sum 16 waves -> out + autoregressive feedback
      float s = bo;
#pragma unroll
      for (int u = 0; u < 16; ++u) s += red[tid * 16 + u];
      out[(long)(b0 + tid) * OUTLEN + td] = s;
      _Float16 hs = (_Float16)s;
      uH[tid * PITCH + 257] = hs;
      uL[tid * PITCH + 257] = (_Float16)(s - (float)hs);
    }
  }
}

extern "C" void kernel_launch(void* const* d_in, const int* in_sizes, int n_in,
                              void* d_out, int out_size, void* d_ws, size_t ws_size,
                              hipStream_t stream) {
  const float* x    = (const float*)d_in[0];
  const float* eWih = (const float*)d_in[1];
  const float* eWhh = (const float*)d_in[2];
  const float* eb   = (const float*)d_in[3];
  const float* dWih = (const float*)d_in[4];
  const float* dWhh = (const float*)d_in[5];
  const float* db   = (const float*)d_in[6];
  const float* Wout = (const float*)d_in[7];
  const float* bout = (const float*)d_in[8];
  float* out = (float*)d_out;

  _Float16* E  = (_Float16*)d_ws;        // 589824 B
  _Float16* Dw = E + NFRAG * 8;          // 589824 B

  prep_kernel<<<dim3((NFRAG * 8 + 255) / 256), dim3(256), 0, stream>>>(
      eWih, eWhh, eb, dWih, dWhh, db, E, Dw);
  seq2seq_kernel<<<dim3(NBLK), dim3(1024), 0, stream>>>(
      x, E, Dw, Wout, bout, out);
}